// Round 8
// baseline (20.874 us; speedup 1.0000x reference)
//
#include <hip/hip_runtime.h>

#define DIM 7
#define HD  32   // hidden width
#define P2  21   // C(7,2)
#define P3  35   // C(7,3)
#define BLK 256
#define NT  3    // 16-wide output-col tiles (48 cols, 35 used)
#define TPW 4    // 16-row tiles per wave
#define WPB (BLK / 64)
#define WSLAB (TPW * 16 * DIM)   // 448 floats of x per wave
#define OBUF  (16 * P3)          // 560 floats: one tile's output (2240 B)

typedef __attribute__((ext_vector_type(8))) _Float16 half8v;  // MFMA A/B operand
typedef __attribute__((ext_vector_type(4))) float  float4v;   // MFMA accumulator

// Lexicographic triples (i<j<k) from 7 — combination index -> (i,j,k)
static __device__ const int TI[P3] = {
  0,0,0,0,0,0,0,0,0,0,0,0,0,0,0,
  1,1,1,1,1,1,1,1,1,1,
  2,2,2,2,2,2,
  3,3,3,
  4};
static __device__ const int TJ[P3] = {
  1,1,1,1,1, 2,2,2,2, 3,3,3, 4,4, 5,
  2,2,2,2, 3,3,3, 4,4, 5,
  3,3,3, 4,4, 5,
  4,4, 5,
  5};
static __device__ const int TK[P3] = {
  2,3,4,5,6, 3,4,5,6, 4,5,6, 5,6, 6,
  3,4,5,6, 4,5,6, 5,6, 6,
  4,5,6, 5,6, 6,
  5,6, 6,
  6};

__device__ __forceinline__ int pos2(int a, int b) {
  return a * 6 - (a * (a - 1)) / 2 + (b - a - 1);
}

// Pre-kernel: M as f16, col-major ws[col*HD + h], cols 35..47 zero. 1536 entries.
__global__ void build_m(const float* __restrict__ W1,
                        const float* __restrict__ W2,
                        _Float16* __restrict__ mws)
{
  for (int idx = threadIdx.x; idx < NT * 16 * HD; idx += BLK) {
    int col = idx >> 5;
    int h   = idx & (HD - 1);
    float val = 0.f;
    if (col < P3) {
      int i = TI[col], j = TJ[col], k = TK[col];
      val = W1[i * HD + h] * W2[h * P2 + pos2(j, k)]
          - W1[j * HD + h] * W2[h * P2 + pos2(i, k)]
          + W1[k * HD + h] * W2[h * P2 + pos2(i, j)];
    }
    mws[idx] = (_Float16)val;
  }
}

__global__ __launch_bounds__(BLK)
void dform_kernel(const float* __restrict__ x,
                  const float* __restrict__ W1,
                  const _Float16* __restrict__ mws,
                  float* __restrict__ out, int B)
{
  // wave-private scratch: x slab (448 f) then per-tile out staging (560 f)
  __shared__ float ls[WPB][OBUF];

  const int tid  = threadIdx.x;
  const int lane = tid & 63;
  const int wid  = tid >> 6;
  const int lrow = lane & 15;   // out row within tile (= D col)
  const int lgrp = lane >> 4;   // k-group; D-row group (= out col group)
  const int h0   = lgrp * 8;

  float* xw = &ls[wid][0];

  // --- stage this wave's x slab: aligned, coalesced, deduplicated ---
  const int gw = blockIdx.x * WPB + wid;          // global wave id
  const int tb = gw * TPW;                        // first tile of this wave
  const long long xbase = (long long)gw * WSLAB;  // float index into x
  if (xbase + WSLAB <= (long long)B * DIM) {
    const float4* src = reinterpret_cast<const float4*>(x + xbase);  // 16B-aligned
    float4* dst = reinterpret_cast<float4*>(xw);
    dst[lane] = src[lane];
    if (lane < WSLAB / 4 - 64) dst[lane + 64] = src[lane + 64];  // lanes 0..47
  } else {
    for (int i = lane; i < WSLAB; i += 64) {
      long long g = xbase + i;
      xw[i] = (g < (long long)B * DIM) ? x[g] : 0.f;
    }
  }

  // --- per-lane W1 columns: w1r[j][e] = W1[j][h0+e]  (L2-hot, coalesced-ish) ---
  float w1r[DIM][8];
  #pragma unroll
  for (int j = 0; j < DIM; ++j) {
    float4 p0 = *reinterpret_cast<const float4*>(&W1[j * HD + h0]);
    float4 p1 = *reinterpret_cast<const float4*>(&W1[j * HD + h0 + 4]);
    w1r[j][0] = p0.x; w1r[j][1] = p0.y; w1r[j][2] = p0.z; w1r[j][3] = p0.w;
    w1r[j][4] = p1.x; w1r[j][5] = p1.y; w1r[j][6] = p1.z; w1r[j][7] = p1.w;
  }

  // --- A-operand fragments from global M table (per c: 1024B contiguous, L2) ---
  half8v mfrag[NT];
  #pragma unroll
  for (int c = 0; c < NT; ++c)
    mfrag[c] = *reinterpret_cast<const half8v*>(&mws[(c * 16 + lrow) * HD + h0]);

  // --- x rows from LDS into registers (wave-synchronous; in-order DS pipe) ---
  __builtin_amdgcn_wave_barrier();
  float xr[TPW][DIM];
  #pragma unroll
  for (int i = 0; i < TPW; ++i)
    #pragma unroll
    for (int j = 0; j < DIM; ++j)
      xr[i][j] = xw[(i * 16 + lrow) * DIM + j];
  __builtin_amdgcn_wave_barrier();  // slab dead; buffer reused for out staging

  float* ob = &ls[wid][0];

  #pragma unroll
  for (int i = 0; i < TPW; ++i) {
    const int t = tb + i;
    if (t * 16 >= B) break;

    // B-operand: B[k=h0+e][j=lrow] = cos(x[row] . W1[:,h0+e])
    half8v cfrag;
    #pragma unroll
    for (int e = 0; e < 8; ++e) {
      float tv = 0.f;
      #pragma unroll
      for (int j = 0; j < DIM; ++j) tv = fmaf(xr[i][j], w1r[j][e], tv);
      cfrag[e] = (_Float16)__cosf(tv);
    }

    // D = M^T · cos^T: lane holds out[row=t*16+lrow][c*16 + lgrp*4 + r]
    float4v acc[NT];
    #pragma unroll
    for (int c = 0; c < NT; ++c) {
      acc[c][0] = 0.f; acc[c][1] = 0.f; acc[c][2] = 0.f; acc[c][3] = 0.f;
      acc[c] = __builtin_amdgcn_mfma_f32_16x16x32_f16(mfrag[c], cfrag, acc[c], 0, 0, 0);
    }

    // --- stage tile output in LDS (row-major 16 x 35) ---
    {
      float* rp = ob + lrow * P3;
      const int cb = lgrp * 4;
      *reinterpret_cast<float4*>(rp + cb) =
          make_float4(acc[0][0], acc[0][1], acc[0][2], acc[0][3]);
      *reinterpret_cast<float4*>(rp + 16 + cb) =
          make_float4(acc[1][0], acc[1][1], acc[1][2], acc[1][3]);
      if (lgrp == 0) {
        *reinterpret_cast<float2*>(rp + 32) = make_float2(acc[2][0], acc[2][1]);
        rp[34] = acc[2][2];
      }
    }
    __builtin_amdgcn_wave_barrier();

    // --- contiguous coalesced store: 560 floats = 140 float4 ---
    if ((long long)(t + 1) * 16 <= B) {
      float4* dst = reinterpret_cast<float4*>(out + (long long)t * OBUF);
      const float4* src = reinterpret_cast<const float4*>(ob);
      dst[lane]      = src[lane];
      dst[lane + 64] = src[lane + 64];
      if (lane < OBUF / 4 - 128) dst[lane + 128] = src[lane + 128];  // 12 lanes
    } else {
      long long base = (long long)t * OBUF;
      long long lim  = (long long)B * P3;
      for (int q = lane; q < OBUF; q += 64)
        if (base + q < lim) out[base + q] = ob[q];
    }
    __builtin_amdgcn_wave_barrier();  // ob reused next tile
  }
}

extern "C" void kernel_launch(void* const* d_in, const int* in_sizes, int n_in,
                              void* d_out, int out_size, void* d_ws, size_t ws_size,
                              hipStream_t stream) {
  const float* x  = (const float*)d_in[0];
  const float* W1 = (const float*)d_in[1];
  const float* W2 = (const float*)d_in[2];
  float* out = (float*)d_out;
  _Float16* mws = (_Float16*)d_ws;  // 1536 * 2 = 3 KB
  const int B = in_sizes[0] / DIM;
  const int ntiles = (B + 15) / 16;
  const int waves  = (ntiles + TPW - 1) / TPW;
  const int grid   = (waves + WPB - 1) / WPB;  // 1024 for B=262144
  hipLaunchKernelGGL(build_m, dim3(1), dim3(BLK), 0, stream, W1, W2, mws);
  hipLaunchKernelGGL(dform_kernel, dim3(grid), dim3(BLK), 0, stream,
                     x, W1, mws, out, B);
}